// Round 1
// baseline (45.636 us; speedup 1.0000x reference)
//
#include <hip/hip_runtime.h>
#include <math.h>

#define DIMS 512
#define BATCH 1024
#define CLS 256

// eps constants from reference
#define EPS_PD 1e-6f
#define DEPS2 (512.0f * 1e-6f * 1e-6f)   // D * eps^2 = 5.12e-10
#define EPS_NORM 1e-12f

__device__ __forceinline__ float waveReduceSum(float v) {
#pragma unroll
  for (int off = 32; off > 0; off >>= 1)
    v += __shfl_xor(v, off, 64);
  return v;
}

// K1: grid = 256 (weight rows) + 1024 (feature rows), block = 64 (one wave).
// Weights: write normalized row to w_norm, Sw[row] = sum of normalized comps.
// Features: write rnF[row] = 1/max(||f||,eps), Sf[row] = sum of normalized comps.
// Block 0 also zeroes the protoc-sum accumulator.
__global__ __launch_bounds__(64) void k_norm(
    const float* __restrict__ feat, const float* __restrict__ wt,
    float* __restrict__ w_norm, float* __restrict__ Sw,
    float* __restrict__ rnF, float* __restrict__ Sf,
    float* __restrict__ S_accum) {
  const int b = blockIdx.x;
  const int lane = threadIdx.x;
  if (b == 0 && lane == 0) *S_accum = 0.f;

  const bool isW = (b < CLS);
  const int row = isW ? b : (b - CLS);
  const float* src = isW ? (wt + (size_t)row * DIMS) : (feat + (size_t)row * DIMS);
  const float4* s4 = (const float4*)src;

  float4 a = s4[lane];        // d in [lane*4, lane*4+4)
  float4 c = s4[lane + 64];   // d in [256+lane*4, ...)

  float ss = a.x*a.x + a.y*a.y + a.z*a.z + a.w*a.w
           + c.x*c.x + c.y*c.y + c.z*c.z + c.w*c.w;
  float sm = a.x + a.y + a.z + a.w + c.x + c.y + c.z + c.w;
  ss = waveReduceSum(ss);
  sm = waveReduceSum(sm);
  const float rn = 1.f / fmaxf(sqrtf(ss), EPS_NORM);

  if (isW) {
    float4* dst = (float4*)(w_norm + (size_t)row * DIMS);
    a.x *= rn; a.y *= rn; a.z *= rn; a.w *= rn;
    c.x *= rn; c.y *= rn; c.z *= rn; c.w *= rn;
    dst[lane] = a;
    dst[lane + 64] = c;
    if (lane == 0) Sw[row] = sm * rn;
  } else {
    if (lane == 0) { rnF[row] = rn; Sf[row] = sm * rn; }
  }
}

// K2: grid = 256 (row i of protoc), block = 256 (col j).
// dist^2(i,j) = 2 - 2*wi.wj + 2*eps*(Sw_i - Sw_j) + D*eps^2
// Sum dist over j per block, one atomicAdd per block.
__global__ __launch_bounds__(256) void k_protoc(
    const float* __restrict__ w_norm, const float* __restrict__ Sw,
    float* __restrict__ S_accum) {
  const int i = blockIdx.x;
  const int j = threadIdx.x;
  const float4* wi = (const float4*)(w_norm + (size_t)i * DIMS);
  const float4* wj = (const float4*)(w_norm + (size_t)j * DIMS);

  float acc = 0.f;
#pragma unroll 4
  for (int d4 = 0; d4 < DIMS / 4; ++d4) {
    float4 x = wi[d4];   // broadcast (same addr across lanes) -> L1 hit
    float4 y = wj[d4];
    acc += x.x*y.x + x.y*y.y + x.z*y.z + x.w*y.w;
  }
  const float d2 = 2.f - 2.f*acc + 2.f*EPS_PD*(Sw[i] - Sw[j]) + DEPS2;
  const float dist = sqrtf(fmaxf(d2, 0.f));

  __shared__ float red[4];
  float wsum = waveReduceSum(dist);
  const int wid = j >> 6;
  if ((j & 63) == 0) red[wid] = wsum;
  __syncthreads();
  if (j == 0) atomicAdd(S_accum, red[0] + red[1] + red[2] + red[3]);
}

// K3: grid = 256 (4 feature rows each), block = 256 (one class col per thread).
// dot(f_norm_i, w_j) = rnF[i] * (f_raw_i . w_j); epilogue fused.
__global__ __launch_bounds__(256) void k_main(
    const float* __restrict__ feat, const float* __restrict__ w_norm,
    const float* __restrict__ Sw, const float* __restrict__ rnF,
    const float* __restrict__ Sf, const float* __restrict__ S_accum,
    const float* __restrict__ dscale, const int* __restrict__ use_ds,
    float* __restrict__ out) {
  const int j = threadIdx.x;
  const int i0 = blockIdx.x * 4;

  const float4* wj = (const float4*)(w_norm + (size_t)j * DIMS);
  const float4* f0 = (const float4*)(feat + (size_t)(i0 + 0) * DIMS);
  const float4* f1 = (const float4*)(feat + (size_t)(i0 + 1) * DIMS);
  const float4* f2 = (const float4*)(feat + (size_t)(i0 + 2) * DIMS);
  const float4* f3 = (const float4*)(feat + (size_t)(i0 + 3) * DIMS);

  float acc0 = 0.f, acc1 = 0.f, acc2 = 0.f, acc3 = 0.f;
#pragma unroll 2
  for (int d4 = 0; d4 < DIMS / 4; ++d4) {
    const float4 w = wj[d4];
    float4 a;
    a = f0[d4]; acc0 += a.x*w.x + a.y*w.y + a.z*w.z + a.w*w.w;
    a = f1[d4]; acc1 += a.x*w.x + a.y*w.y + a.z*w.z + a.w*w.w;
    a = f2[d4]; acc2 += a.x*w.x + a.y*w.y + a.z*w.z + a.w*w.w;
    a = f3[d4]; acc3 += a.x*w.x + a.y*w.y + a.z*w.z + a.w*w.w;
  }

  const float Ssc = 0.1f * (*S_accum);
  const float sc = (use_ds[0] != 0) ? fabsf(dscale[0]) : 1.0f;
  const float swj = Sw[j];

  float accs[4] = {acc0, acc1, acc2, acc3};
#pragma unroll
  for (int r = 0; r < 4; ++r) {
    const int i = i0 + r;
    const float dot = accs[r] * rnF[i];
    const float d2 = 2.f - 2.f*dot + 2.f*EPS_PD*(Sf[i] - swj) + DEPS2;
    const float dist = sqrtf(fmaxf(d2, 0.f));
    out[(size_t)i * CLS + j] = (Ssc - dist) * sc;
  }
}

extern "C" void kernel_launch(void* const* d_in, const int* in_sizes, int n_in,
                              void* d_out, int out_size, void* d_ws, size_t ws_size,
                              hipStream_t stream) {
  const float* feat = (const float*)d_in[0];     // [1024,512]
  const float* wt   = (const float*)d_in[1];     // [256,512]
  const float* ds   = (const float*)d_in[2];     // [1]
  const int*   use  = (const int*)d_in[3];       // scalar
  float* out = (float*)d_out;                    // [1024,256]

  float* w = (float*)d_ws;
  float* w_norm = w;                 // 256*512 = 131072 floats
  float* Sw     = w + 131072;        // 256
  float* rnF    = w + 131328;        // 1024
  float* Sf     = w + 132352;        // 1024
  float* S      = w + 133376;        // 1

  k_norm<<<CLS + BATCH, 64, 0, stream>>>(feat, wt, w_norm, Sw, rnF, Sf, S);
  k_protoc<<<CLS, 256, 0, stream>>>(w_norm, Sw, S);
  k_main<<<BATCH / 4, 256, 0, stream>>>(feat, w_norm, Sw, rnF, Sf, S, ds, use, out);
}

// Round 2
// 40.724 us; speedup vs baseline: 1.1206x; 1.1206x over previous
//
#include <hip/hip_runtime.h>
#include <math.h>

#define DIMS 512
#define BATCH 1024
#define CLS 256

// eps constants from reference
#define EPS_PD 1e-6f
#define DEPS2 (512.0f * 1e-6f * 1e-6f)   // D * eps^2 = 5.12e-10
#define EPS_NORM 1e-12f

__device__ __forceinline__ float waveReduceSum(float v) {
#pragma unroll
  for (int off = 32; off > 0; off >>= 1)
    v += __shfl_xor(v, off, 64);
  return v;
}

// K1: grid = 256 (weight rows) + 1024 (feature rows), block = 64 (one wave).
// Weights: write normalized row to w_norm, Sw[row] = sum of normalized comps.
// Features: write rnF[row] = 1/max(||f||,eps), Sf[row] = sum of normalized comps.
// Block 0 also zeroes the protoc-sum accumulator.
__global__ __launch_bounds__(64) void k_norm(
    const float* __restrict__ feat, const float* __restrict__ wt,
    float* __restrict__ w_norm, float* __restrict__ Sw,
    float* __restrict__ rnF, float* __restrict__ Sf,
    float* __restrict__ S_accum) {
  const int b = blockIdx.x;
  const int lane = threadIdx.x;
  if (b == 0 && lane == 0) *S_accum = 0.f;

  const bool isW = (b < CLS);
  const int row = isW ? b : (b - CLS);
  const float* src = isW ? (wt + (size_t)row * DIMS) : (feat + (size_t)row * DIMS);
  const float4* s4 = (const float4*)src;

  float4 a = s4[lane];        // d in [lane*4, lane*4+4)
  float4 c = s4[lane + 64];   // d in [256+lane*4, ...)

  float ss = a.x*a.x + a.y*a.y + a.z*a.z + a.w*a.w
           + c.x*c.x + c.y*c.y + c.z*c.z + c.w*c.w;
  float sm = a.x + a.y + a.z + a.w + c.x + c.y + c.z + c.w;
  ss = waveReduceSum(ss);
  sm = waveReduceSum(sm);
  const float rn = 1.f / fmaxf(sqrtf(ss), EPS_NORM);

  if (isW) {
    float4* dst = (float4*)(w_norm + (size_t)row * DIMS);
    a.x *= rn; a.y *= rn; a.z *= rn; a.w *= rn;
    c.x *= rn; c.y *= rn; c.z *= rn; c.w *= rn;
    dst[lane] = a;
    dst[lane + 64] = c;
    if (lane == 0) Sw[row] = sm * rn;
  } else {
    if (lane == 0) { rnF[row] = rn; Sf[row] = sm * rn; }
  }
}

// K2: gram-matrix tiled GEMM over w_norm [256x256, K=512].
// grid = (16,16) tiles of 16x16; block = 256 threads, 1x1 per thread.
// Coalesced float2 global loads, transposed LDS tiles As[k][m] (pad 17).
// dist(i,j) = sqrt(max(2 - 2*wi.wj + 2*eps*(Sw_i - Sw_j) + D*eps^2, 0));
// block-reduce the 256 dists -> one atomicAdd.
__global__ __launch_bounds__(256) void k_protoc(
    const float* __restrict__ w_norm, const float* __restrict__ Sw,
    float* __restrict__ S_accum) {
  __shared__ float As[32][17];
  __shared__ float Bs[32][17];
  __shared__ float red[4];

  const int t  = threadIdx.x;
  const int tx = t & 15;        // j within tile
  const int ty = t >> 4;        // i within tile
  const int i0 = blockIdx.y * 16;
  const int j0 = blockIdx.x * 16;

  const int lrow = t >> 4;        // 0..15 (row loaded by this thread)
  const int lk   = (t & 15) * 2;  // k offset within tile

  float acc = 0.f;
  for (int k0 = 0; k0 < DIMS; k0 += 32) {
    const float2 a = *(const float2*)(w_norm + (size_t)(i0 + lrow) * DIMS + k0 + lk);
    const float2 b = *(const float2*)(w_norm + (size_t)(j0 + lrow) * DIMS + k0 + lk);
    __syncthreads();
    As[lk + 0][lrow] = a.x; As[lk + 1][lrow] = a.y;
    Bs[lk + 0][lrow] = b.x; Bs[lk + 1][lrow] = b.y;
    __syncthreads();
#pragma unroll
    for (int k = 0; k < 32; ++k)
      acc += As[k][ty] * Bs[k][tx];
  }

  const float d2 = 2.f - 2.f * acc + 2.f * EPS_PD * (Sw[i0 + ty] - Sw[j0 + tx]) + DEPS2;
  const float dist = sqrtf(fmaxf(d2, 0.f));

  float ws = waveReduceSum(dist);
  if ((t & 63) == 0) red[t >> 6] = ws;
  __syncthreads();
  if (t == 0) atomicAdd(S_accum, red[0] + red[1] + red[2] + red[3]);
}

// K3: main GEMM feat[1024x512] . w_norm^T[512x256] with fused epilogue.
// grid = (8,32) tiles of 32x32; block = 256 threads (16x16), 2x2 per thread.
// Coalesced float4 global loads, transposed LDS tiles (pad 34), float2
// LDS compute reads (A broadcast, B spread over all banks 2-way).
__global__ __launch_bounds__(256) void k_main(
    const float* __restrict__ feat, const float* __restrict__ w_norm,
    const float* __restrict__ Sw, const float* __restrict__ rnF,
    const float* __restrict__ Sf, const float* __restrict__ S_accum,
    const float* __restrict__ dscale, const int* __restrict__ use_ds,
    float* __restrict__ out) {
  __shared__ float As[32][34];
  __shared__ float Bs[32][34];

  const int t  = threadIdx.x;
  const int tx = t & 15;        // class pair index
  const int ty = t >> 4;        // row pair index
  const int i0 = blockIdx.y * 32;   // feature rows
  const int j0 = blockIdx.x * 32;   // classes

  const int lrow = t >> 3;        // 0..31
  const int lk   = (t & 7) * 4;   // 0,4,...,28

  float acc00 = 0.f, acc01 = 0.f, acc10 = 0.f, acc11 = 0.f;

  for (int k0 = 0; k0 < DIMS; k0 += 32) {
    const float4 a = *(const float4*)(feat + (size_t)(i0 + lrow) * DIMS + k0 + lk);
    const float4 b = *(const float4*)(w_norm + (size_t)(j0 + lrow) * DIMS + k0 + lk);
    __syncthreads();
    As[lk + 0][lrow] = a.x; As[lk + 1][lrow] = a.y;
    As[lk + 2][lrow] = a.z; As[lk + 3][lrow] = a.w;
    Bs[lk + 0][lrow] = b.x; Bs[lk + 1][lrow] = b.y;
    Bs[lk + 2][lrow] = b.z; Bs[lk + 3][lrow] = b.w;
    __syncthreads();
#pragma unroll
    for (int k = 0; k < 32; ++k) {
      const float2 av = *(const float2*)&As[k][ty * 2];
      const float2 bv = *(const float2*)&Bs[k][tx * 2];
      acc00 += av.x * bv.x; acc01 += av.x * bv.y;
      acc10 += av.y * bv.x; acc11 += av.y * bv.y;
    }
  }

  const float Ssc = 0.1f * (*S_accum);
  const float sc = (use_ds[0] != 0) ? fabsf(dscale[0]) : 1.0f;

  const int i = i0 + ty * 2;
  const int j = j0 + tx * 2;
  const float rn0 = rnF[i], rn1 = rnF[i + 1];
  const float sf0 = Sf[i], sf1 = Sf[i + 1];
  const float sw0 = Sw[j], sw1 = Sw[j + 1];

  float d2, dist;
  d2 = 2.f - 2.f * (acc00 * rn0) + 2.f * EPS_PD * (sf0 - sw0) + DEPS2;
  dist = sqrtf(fmaxf(d2, 0.f));
  out[(size_t)i * CLS + j] = (Ssc - dist) * sc;

  d2 = 2.f - 2.f * (acc01 * rn0) + 2.f * EPS_PD * (sf0 - sw1) + DEPS2;
  dist = sqrtf(fmaxf(d2, 0.f));
  out[(size_t)i * CLS + j + 1] = (Ssc - dist) * sc;

  d2 = 2.f - 2.f * (acc10 * rn1) + 2.f * EPS_PD * (sf1 - sw0) + DEPS2;
  dist = sqrtf(fmaxf(d2, 0.f));
  out[(size_t)(i + 1) * CLS + j] = (Ssc - dist) * sc;

  d2 = 2.f - 2.f * (acc11 * rn1) + 2.f * EPS_PD * (sf1 - sw1) + DEPS2;
  dist = sqrtf(fmaxf(d2, 0.f));
  out[(size_t)(i + 1) * CLS + j + 1] = (Ssc - dist) * sc;
}

extern "C" void kernel_launch(void* const* d_in, const int* in_sizes, int n_in,
                              void* d_out, int out_size, void* d_ws, size_t ws_size,
                              hipStream_t stream) {
  const float* feat = (const float*)d_in[0];     // [1024,512]
  const float* wt   = (const float*)d_in[1];     // [256,512]
  const float* ds   = (const float*)d_in[2];     // [1]
  const int*   use  = (const int*)d_in[3];       // scalar
  float* out = (float*)d_out;                    // [1024,256]

  float* w = (float*)d_ws;
  float* w_norm = w;                 // 256*512 = 131072 floats
  float* Sw     = w + 131072;        // 256
  float* rnF    = w + 131328;        // 1024
  float* Sf     = w + 132352;        // 1024
  float* S      = w + 133376;        // 1

  k_norm<<<CLS + BATCH, 64, 0, stream>>>(feat, wt, w_norm, Sw, rnF, Sf, S);
  k_protoc<<<dim3(16, 16), 256, 0, stream>>>(w_norm, Sw, S);
  k_main<<<dim3(8, 32), 256, 0, stream>>>(feat, w_norm, Sw, rnF, Sf, S, ds, use, out);
}

// Round 7
// 20.836 us; speedup vs baseline: 2.1902x; 1.9545x over previous
//
#include <hip/hip_runtime.h>
#include <math.h>

#define DIMS 512
#define BATCH 1024
#define CLS 256
#define ROWS (BATCH + CLS)   // 1280 stacked rows: [f_norm; w_norm]

#define EPS_PD 1e-6f
#define DEPS2 (512.0f * 1e-6f * 1e-6f)   // D * eps^2
#define EPS_NORM 1e-12f

typedef short bf16x8 __attribute__((ext_vector_type(8)));   // 8 bf16 = 4 VGPRs
typedef float f32x4 __attribute__((ext_vector_type(4)));

__device__ __forceinline__ float waveReduceSum(float v) {
#pragma unroll
  for (int off = 32; off > 0; off >>= 1)
    v += __shfl_xor(v, off, 64);
  return v;
}

// round-to-nearest-even float -> bf16 (inputs are normal floats; NaN not expected)
__device__ __forceinline__ unsigned short f2bf(float x) {
  unsigned int u = __float_as_uint(x);
  u += 0x7fffu + ((u >> 16) & 1u);
  return (unsigned short)(u >> 16);
}

// K1: grid = 1280, block = 64. Row r<1024 -> feat, else weight row r-1024.
// Normalize row, cast to bf16 into fnw[r][512]; Srow[r] = sum of normalized comps.
__global__ __launch_bounds__(64) void k_norm(
    const float* __restrict__ feat, const float* __restrict__ wt,
    unsigned short* __restrict__ fnw, float* __restrict__ Srow) {
  const int r = blockIdx.x;
  const int lane = threadIdx.x;
  const float* src = (r < BATCH) ? (feat + (size_t)r * DIMS)
                                 : (wt + (size_t)(r - BATCH) * DIMS);
  const float4* s4 = (const float4*)src;

  float4 a = s4[lane];        // d = lane*4 .. +3
  float4 c = s4[lane + 64];   // d = 256 + lane*4 .. +3

  float ss = a.x*a.x + a.y*a.y + a.z*a.z + a.w*a.w
           + c.x*c.x + c.y*c.y + c.z*c.z + c.w*c.w;
  float sm = a.x + a.y + a.z + a.w + c.x + c.y + c.z + c.w;
  ss = waveReduceSum(ss);
  sm = waveReduceSum(sm);
  const float rn = 1.f / fmaxf(sqrtf(ss), EPS_NORM);

  ushort4 pa, pc;
  pa.x = f2bf(a.x * rn); pa.y = f2bf(a.y * rn);
  pa.z = f2bf(a.z * rn); pa.w = f2bf(a.w * rn);
  pc.x = f2bf(c.x * rn); pc.y = f2bf(c.y * rn);
  pc.z = f2bf(c.z * rn); pc.w = f2bf(c.w * rn);

  ushort4* dst = (ushort4*)(fnw + (size_t)r * DIMS);
  dst[lane] = pa;          // d = lane*4
  dst[lane + 64] = pc;     // d = 256 + lane*4

  if (lane == 0) Srow[r] = sm * rn;
}

// K2: bf16 MFMA GEMM. dots[1280x256] = fnw[1280x512] . (w rows of fnw)^T.
// One wave per 32x32 tile; grid (40, 8); no LDS; fragments from global (L2-hot).
__global__ __launch_bounds__(64) void k_gemm(
    const unsigned short* __restrict__ fnw, float* __restrict__ dots) {
  const int lane = threadIdx.x;
  const int r0 = blockIdx.x * 32;          // output rows (stacked)
  const int j0 = blockIdx.y * 32;          // class cols

  const int lm = lane & 15;                // row/col within fragment
  const int lk = (lane >> 4) * 8;          // k sub-block (0,8,16,24)

  // A fragment rows
  const unsigned short* arow0 = fnw + (size_t)(r0 + lm) * DIMS + lk;
  const unsigned short* arow1 = fnw + (size_t)(r0 + 16 + lm) * DIMS + lk;
  // B fragment rows: B[k][col] = W[col][k], W rows start at stacked row 1024
  const unsigned short* brow0 = fnw + (size_t)(BATCH + j0 + lm) * DIMS + lk;
  const unsigned short* brow1 = fnw + (size_t)(BATCH + j0 + 16 + lm) * DIMS + lk;

  f32x4 acc00 = {0.f,0.f,0.f,0.f}, acc01 = {0.f,0.f,0.f,0.f};
  f32x4 acc10 = {0.f,0.f,0.f,0.f}, acc11 = {0.f,0.f,0.f,0.f};

#pragma unroll
  for (int k0 = 0; k0 < DIMS; k0 += 32) {
    const bf16x8 a0 = *(const bf16x8*)(arow0 + k0);
    const bf16x8 a1 = *(const bf16x8*)(arow1 + k0);
    const bf16x8 b0 = *(const bf16x8*)(brow0 + k0);
    const bf16x8 b1 = *(const bf16x8*)(brow1 + k0);
    acc00 = __builtin_amdgcn_mfma_f32_16x16x32_bf16(a0, b0, acc00, 0, 0, 0);
    acc01 = __builtin_amdgcn_mfma_f32_16x16x32_bf16(a0, b1, acc01, 0, 0, 0);
    acc10 = __builtin_amdgcn_mfma_f32_16x16x32_bf16(a1, b0, acc10, 0, 0, 0);
    acc11 = __builtin_amdgcn_mfma_f32_16x16x32_bf16(a1, b1, acc11, 0, 0, 0);
  }

  // C/D layout: col = lane&15, row = (lane>>4)*4 + q  (m89-verified)
  const int crow = (lane >> 4) * 4;
  const int ccol = lane & 15;
#pragma unroll
  for (int q = 0; q < 4; ++q) {
    dots[(size_t)(r0 + crow + q) * CLS + (j0 + ccol)]           = acc00[q];
    dots[(size_t)(r0 + crow + q) * CLS + (j0 + 16 + ccol)]      = acc01[q];
    dots[(size_t)(r0 + 16 + crow + q) * CLS + (j0 + ccol)]      = acc10[q];
    dots[(size_t)(r0 + 16 + crow + q) * CLS + (j0 + 16 + ccol)] = acc11[q];
  }
}

// K3: reduce protoc block (stacked rows 1024..1279) to 64 deterministic partials.
// grid = 64, block = 256; each thread one float4 of dots.
__global__ __launch_bounds__(256) void k_red(
    const float* __restrict__ dots, const float* __restrict__ Srow,
    float* __restrict__ partial) {
  const int b = blockIdx.x;
  const int t = threadIdx.x;
  const int g = b * 1024 + t * 4;          // element index within 256x256 block
  const int i = g >> 8;                    // protoc row
  const int j = g & 255;                   // protoc col (j%4==0)

  const float4 d4 = *(const float4*)(dots + (size_t)BATCH * CLS + g);
  const float swi = Srow[BATCH + i];
  const float4 swj = *(const float4*)(Srow + BATCH + j);

  float s = 0.f;
  const float dot[4] = {d4.x, d4.y, d4.z, d4.w};
  const float sw[4] = {swj.x, swj.y, swj.z, swj.w};
#pragma unroll
  for (int e = 0; e < 4; ++e) {
    float dist;
    if (i == j + e) {
      dist = sqrtf(DEPS2);                 // exact diagonal (self-distance)
    } else {
      const float d2 = 2.f - 2.f * dot[e] + 2.f * EPS_PD * (swi - sw[e]) + DEPS2;
      dist = sqrtf(fmaxf(d2, 0.f));
    }
    s += dist;
  }

  __shared__ float red[4];
  float ws = waveReduceSum(s);
  if ((t & 63) == 0) red[t >> 6] = ws;
  __syncthreads();
  if (t == 0) partial[b] = red[0] + red[1] + red[2] + red[3];
}

// K4: epilogue over the 1024x256 main block. grid = 256, block = 256, float4 each.
__global__ __launch_bounds__(256) void k_epi(
    const float* __restrict__ dots, const float* __restrict__ Srow,
    const float* __restrict__ partial, const float* __restrict__ dscale,
    const int* __restrict__ use_ds, float* __restrict__ out) {
  const int t = threadIdx.x;

  __shared__ float sS;
  if (t < 64) {
    float v = partial[t];
    v = waveReduceSum(v);
    if (t == 0) sS = v;
  }
  __syncthreads();
  const float Ssc = 0.1f * sS;
  const float sc = (use_ds[0] != 0) ? fabsf(dscale[0]) : 1.0f;

  const int g = (blockIdx.x * 256 + t) * 4;  // element index within 1024x256
  const int i = g >> 8;                      // feature row
  const int j = g & 255;                     // class col (j%4==0)

  const float4 d4 = *(const float4*)(dots + g);
  const float sfi = Srow[i];
  const float4 swj = *(const float4*)(Srow + BATCH + j);

  const float dot[4] = {d4.x, d4.y, d4.z, d4.w};
  const float sw[4] = {swj.x, swj.y, swj.z, swj.w};
  float4 o;
  float* op = (float*)&o;
#pragma unroll
  for (int e = 0; e < 4; ++e) {
    const float d2 = 2.f - 2.f * dot[e] + 2.f * EPS_PD * (sfi - sw[e]) + DEPS2;
    const float dist = sqrtf(fmaxf(d2, 0.f));
    op[e] = (Ssc - dist) * sc;
  }
  *(float4*)(out + g) = o;
}

extern "C" void kernel_launch(void* const* d_in, const int* in_sizes, int n_in,
                              void* d_out, int out_size, void* d_ws, size_t ws_size,
                              hipStream_t stream) {
  const float* feat = (const float*)d_in[0];     // [1024,512]
  const float* wt   = (const float*)d_in[1];     // [256,512]
  const float* ds   = (const float*)d_in[2];     // [1]
  const int*   use  = (const int*)d_in[3];       // scalar
  float* out = (float*)d_out;                    // [1024,256] fp32

  // ws layout (bytes): fnw bf16 1280*512*2 = 1,310,720 ; then floats
  unsigned short* fnw = (unsigned short*)d_ws;
  float* fbase   = (float*)((char*)d_ws + (size_t)ROWS * DIMS * 2);
  float* Srow    = fbase;                        // 1280
  float* partial = fbase + ROWS;                 // 64
  float* dots    = fbase + ROWS + 64;            // 1280*256 (16B-aligned: offset 1344 floats)

  k_norm<<<ROWS, 64, 0, stream>>>(feat, wt, fnw, Srow);
  k_gemm<<<dim3(ROWS / 32, CLS / 32), 64, 0, stream>>>(fnw, dots);
  k_red<<<64, 256, 0, stream>>>(dots, Srow, partial);
  k_epi<<<256, 256, 0, stream>>>(dots, Srow, partial, ds, use, out);
}